// Round 7
// baseline (285.296 us; speedup 1.0000x reference)
//
#include <hip/hip_runtime.h>

#define S_ 4096

typedef __attribute__((ext_vector_type(8))) short short8;
typedef __attribute__((ext_vector_type(4))) float f32x4;

static __device__ __forceinline__ float bf2f(unsigned short u) {
  union { unsigned int i; float f; } v; v.i = ((unsigned int)u) << 16; return v.f;
}
static __device__ __forceinline__ unsigned short f2bf(float f) {
  union { float f; unsigned int i; } v; v.f = f;
  unsigned int r = v.i + 0x7FFFu + ((v.i >> 16) & 1u);
  return (unsigned short)(r >> 16);
}

#define LOAD_LDS16(g, l) __builtin_amdgcn_global_load_lds( \
    (const __attribute__((address_space(1))) void*)(g),     \
    (__attribute__((address_space(3))) void*)(l), 16, 0, 0)

// ---------------------------------------------------------------------------
// Merged casts: x -> bf16 (all 16384 blocks), weights/biases (blocks < 1024).
// Wq/bq pre-scaled by 0.125 (= 1/sqrt(64), exact).
__global__ __launch_bounds__(256) void cast_all(
    const float* __restrict__ x,
    const float* __restrict__ Wq, const float* __restrict__ Wk,
    const float* __restrict__ Wv, const float* __restrict__ Wo,
    const float* __restrict__ bq, const float* __restrict__ bk,
    const float* __restrict__ bv,
    unsigned short* __restrict__ xb, unsigned short* __restrict__ Wcat,
    unsigned short* __restrict__ Wob, float* __restrict__ bcat) {
  const int bid = blockIdx.x;
  int i4 = (bid * 256 + threadIdx.x) * 4;
  float4 v = *(const float4*)(x + i4);
  ushort4 o;
  o.x = f2bf(v.x); o.y = f2bf(v.y); o.z = f2bf(v.z); o.w = f2bf(v.w);
  *(ushort4*)(xb + i4) = o;
  if (bid < 1024) {
    int i = bid * 256 + threadIdx.x;  // 0..262143
    Wcat[i]          = f2bf(Wq[i] * 0.125f);
    Wcat[262144 + i] = f2bf(Wk[i]);
    Wcat[524288 + i] = f2bf(Wv[i]);
    Wob[i]           = f2bf(Wo[i]);
    if (i < 512) { bcat[i] = bq[i] * 0.125f; bcat[512 + i] = bk[i]; bcat[1024 + i] = bv[i]; }
  }
}

// ---------------------------------------------------------------------------
// C[m][n] = sum_k A[m][k]*Bw[n][k] + bias[n], K=512, row-major operands.
// BM=BN=256, BK=64, 8 waves (2Mx4N), per-wave 128x64 = acc[8][4] frags.
// 2-buffer LDS (128 KiB static). Per K-tile: 4 lockstep phases of
// {ds_read subtile -> barrier -> setprio+16 MFMA -> lgkm0 -> barrier}.
// Phase 0 bursts all 8 gload_lds for KT t+1 into the other buffer; the
// boundary vmcnt(0) at phase 3 drains loads issued ~3 phases earlier.
// LDS chunk swizzle: slot sp of row holds chunk sp^(row&7); applied on
// gload SOURCE (inverse) and ds_read address (both-sides rule).
template<int OUT_BF16, int NBX>
__global__ __launch_bounds__(512, 2) void gemm256(
    const unsigned short* __restrict__ A,
    const unsigned short* __restrict__ Bw,
    const float* __restrict__ bias,
    void* __restrict__ Cv) {
  __shared__ unsigned short lds[65536];  // 2 bufs x (A 16384 + B 16384) ushorts
  const int N = NBX * 256;
  const int NWG = 128 * NBX;

  const int tid = threadIdx.x;
  const int lane = tid & 63;
  const int wv = tid >> 6;        // 0..7
  const int wm = wv >> 2;         // 0..1  (M half)
  const int wn = wv & 3;          // 0..3  (N quarter)
  const int r = lane & 15, g = lane >> 4;

  // XCD-aware swizzle (NWG % 8 == 0 -> bijective)
  int id = blockIdx.x;
  id = (id & 7) * (NWG >> 3) + (id >> 3);
  const int by = id / NBX, bx = id % NBX;
  const int m0 = by * 256, n0 = bx * 256;

  // bias preload, pinned BEFORE staging so the vmcnt FIFO starts clean
  float bcol[4];
#pragma unroll
  for (int nj = 0; nj < 4; ++nj) bcol[nj] = bias[n0 + wn * 64 + nj * 16 + r];
  asm volatile("" : "+v"(bcol[0]), "+v"(bcol[1]), "+v"(bcol[2]), "+v"(bcol[3]));

  // staging addresses: per K-tile each wave issues 4 A + 4 B gload_lds.
  // chunk ci = wv*256 + i*64 + lane -> row = wv*32 + i*8 + (lane>>3),
  // slot = lane&7, source chunk = slot ^ (row&7) = (lane&7)^(lane>>3).
  const int srow = lane >> 3;            // 0..7
  const int scs = (lane & 7) ^ srow;     // inverse-swizzled source chunk
  const unsigned short* gA = A + (size_t)(m0 + wv * 32 + srow) * 512 + scs * 8;
  const unsigned short* gB = Bw + (size_t)(n0 + wv * 32 + srow) * 512 + scs * 8;
  const int sdst = wv * 2048;            // + i*512 ushorts (wave-uniform)

  // ds_read offsets (ushort units): physical chunk = (kk*4+g) ^ (r&7)
  const int sw0 = ((0 + g) ^ (r & 7)) * 8;
  const int sw1 = ((4 + g) ^ (r & 7)) * 8;
  const int arow = (wm * 128 + r) * 64;            // + mi*1024
  const int brow = 16384 + (wn * 64 + r) * 64;     // + nj*1024

  f32x4 acc[8][4] = {};

#define STAGE(kt) do {                                              \
    unsigned short* tb_ = lds + (((kt) & 1) << 15);                 \
    _Pragma("unroll") for (int i_ = 0; i_ < 4; ++i_) {              \
      LOAD_LDS16(gA + (kt) * 64 + i_ * 4096, tb_ + sdst + i_ * 512);\
      LOAD_LDS16(gB + (kt) * 64 + i_ * 4096, tb_ + 16384 + sdst + i_ * 512); \
    }                                                               \
  } while (0)

  STAGE(0);
  asm volatile("s_waitcnt vmcnt(0)" ::: "memory");
  __builtin_amdgcn_s_barrier();

#pragma unroll 1
  for (int t = 0; t < 8; ++t) {
    const unsigned short* tb = lds + ((t & 1) << 15);

    // ---- phase 0: 12 ds_reads (A mi 0,1 + all B) + burst-stage KT t+1
    short8 a0[2][2], bfr[4][2];
#pragma unroll
    for (int d = 0; d < 2; ++d) {
      a0[d][0] = *(const short8*)&tb[arow + d * 1024 + sw0];
      a0[d][1] = *(const short8*)&tb[arow + d * 1024 + sw1];
    }
#pragma unroll
    for (int nj = 0; nj < 4; ++nj) {
      bfr[nj][0] = *(const short8*)&tb[brow + nj * 1024 + sw0];
      bfr[nj][1] = *(const short8*)&tb[brow + nj * 1024 + sw1];
    }
    if (t < 7) STAGE(t + 1);
    __builtin_amdgcn_s_barrier();
    __builtin_amdgcn_s_setprio(1);
#pragma unroll
    for (int kk = 0; kk < 2; ++kk)
#pragma unroll
      for (int d = 0; d < 2; ++d)
#pragma unroll
        for (int nj = 0; nj < 4; ++nj)
          acc[d][nj] = __builtin_amdgcn_mfma_f32_16x16x32_bf16(
              a0[d][kk], bfr[nj][kk], acc[d][nj], 0, 0, 0);
    __builtin_amdgcn_s_setprio(0);
    asm volatile("s_waitcnt lgkmcnt(0)" ::: "memory");
    __builtin_amdgcn_s_barrier();

    // ---- phases 1..3: 4 A ds_reads each, B reused from registers
#pragma unroll
    for (int q = 1; q < 4; ++q) {
      short8 aq[2][2];
#pragma unroll
      for (int d = 0; d < 2; ++d) {
        aq[d][0] = *(const short8*)&tb[arow + (2 * q + d) * 1024 + sw0];
        aq[d][1] = *(const short8*)&tb[arow + (2 * q + d) * 1024 + sw1];
      }
      __builtin_amdgcn_s_barrier();
      __builtin_amdgcn_s_setprio(1);
#pragma unroll
      for (int kk = 0; kk < 2; ++kk)
#pragma unroll
        for (int d = 0; d < 2; ++d)
#pragma unroll
          for (int nj = 0; nj < 4; ++nj)
            acc[2 * q + d][nj] = __builtin_amdgcn_mfma_f32_16x16x32_bf16(
                aq[d][kk], bfr[nj][kk], acc[2 * q + d][nj], 0, 0, 0);
      __builtin_amdgcn_s_setprio(0);
      if (q == 3) asm volatile("s_waitcnt vmcnt(0) lgkmcnt(0)" ::: "memory");
      else        asm volatile("s_waitcnt lgkmcnt(0)" ::: "memory");
      __builtin_amdgcn_s_barrier();
    }
  }
#undef STAGE

  // Epilogue. C/D layout: col = lane&15, row = (lane>>4)*4 + j
  const int ldc = N;
#pragma unroll
  for (int nj = 0; nj < 4; ++nj) {
    const int col = n0 + wn * 64 + nj * 16 + r;
#pragma unroll
    for (int mi = 0; mi < 8; ++mi) {
      const int rowb = m0 + wm * 128 + mi * 16 + g * 4;
      f32x4 v = acc[mi][nj];
#pragma unroll
      for (int j = 0; j < 4; ++j) {
        float val = v[j] + bcol[nj];
        size_t off = (size_t)(rowb + j) * ldc + col;
        if (OUT_BF16) ((unsigned short*)Cv)[off] = f2bf(val);
        else          ((float*)Cv)[off] = val;
      }
    }
  }
}

// ---------------------------------------------------------------------------
// Fused sliding-window attention. One WAVE per m (= b*S+s), all 8 heads.
// lane = h*8+c: every q/k/v access is lane*16B -> perfectly coalesced 1KB
// per wave-instruction. Dot over D=64 reduced across the 8 c-lanes of the
// h-group via shfl_xor(1,2,4).
__global__ __launch_bounds__(256) void swa_fused(
    const unsigned short* __restrict__ qkv, unsigned short* __restrict__ attn) {
  const int m = (blockIdx.x * 256 + threadIdx.x) >> 6;  // 0..32767
  const int lane = threadIdx.x & 63;
  const int s = m & (S_ - 1);
  const unsigned short* base = qkv + (size_t)m * 1536 + lane * 8;

  float q[8];
  {
    short8 qv = *(const short8*)base;
#pragma unroll
    for (int j = 0; j < 8; ++j) q[j] = bf2f((unsigned short)qv[j]);
  }

  float sc[5];
#pragma unroll
  for (int w = 0; w < 5; ++w) {
    int s2 = s + w - 2;
    float p = -1e30f;
    if ((unsigned)s2 < (unsigned)S_) {          // wave-uniform
      short8 kv = *(const short8*)(base + (ptrdiff_t)(w - 2) * 1536 + 512);
      float a = 0.f;
#pragma unroll
      for (int j = 0; j < 8; ++j) a += q[j] * bf2f((unsigned short)kv[j]);
      a += __shfl_xor(a, 1);
      a += __shfl_xor(a, 2);
      a += __shfl_xor(a, 4);                    // h-group (8 lanes) reduce
      p = a;
    }
    sc[w] = p;
  }

  float mx = fmaxf(fmaxf(fmaxf(sc[0], sc[1]), fmaxf(sc[2], sc[3])), sc[4]);
  float e[5], sum = 0.f;
#pragma unroll
  for (int w = 0; w < 5; ++w) { e[w] = __expf(sc[w] - mx); sum += e[w]; }
  float inv = 1.0f / sum;

  float o[8] = {0.f, 0.f, 0.f, 0.f, 0.f, 0.f, 0.f, 0.f};
#pragma unroll
  for (int w = 0; w < 5; ++w) {
    int s2 = s + w - 2;
    if ((unsigned)s2 < (unsigned)S_) {
      short8 vv = *(const short8*)(base + (ptrdiff_t)(w - 2) * 1536 + 1024);
      float pw = e[w] * inv;
#pragma unroll
      for (int j = 0; j < 8; ++j) o[j] += pw * bf2f((unsigned short)vv[j]);
    }
  }

  short8 ov;
#pragma unroll
  for (int j = 0; j < 8; ++j) ov[j] = (short)f2bf(o[j]);
  *(short8*)(attn + (size_t)m * 512 + lane * 8) = ov;
}

// ---------------------------------------------------------------------------
extern "C" void kernel_launch(void* const* d_in, const int* in_sizes, int n_in,
                              void* d_out, int out_size, void* d_ws, size_t ws_size,
                              hipStream_t stream) {
  const float* x  = (const float*)d_in[0];
  const float* Wq = (const float*)d_in[1];
  const float* Wk = (const float*)d_in[2];
  const float* Wv = (const float*)d_in[3];
  const float* bq = (const float*)d_in[4];
  const float* bk = (const float*)d_in[5];
  const float* bv = (const float*)d_in[6];
  const float* Wo = (const float*)d_in[7];
  const float* bo = (const float*)d_in[8];
  float* out = (float*)d_out;

  char* ws = (char*)d_ws;
  unsigned short* xb   = (unsigned short*)(ws);               // 33,554,432 B
  unsigned short* qkv  = (unsigned short*)(ws + 33554432);    // 100,663,296 B
  unsigned short* attn = (unsigned short*)(ws + 134217728);   // 33,554,432 B
  unsigned short* Wcat = (unsigned short*)(ws + 167772160);   // 1,572,864 B
  unsigned short* Wob  = (unsigned short*)(ws + 169345024);   // 524,288 B
  float* bcat          = (float*)(ws + 169869312);            // 6,144 B

  cast_all<<<16384, 256, 0, stream>>>(x, Wq, Wk, Wv, Wo, bq, bk, bv,
                                      xb, Wcat, Wob, bcat);
  // QKV projection: M=32768, N=1536 -> 128 by x 6 bx = 768 blocks
  gemm256<1, 6><<<768, 512, 0, stream>>>(xb, Wcat, bcat, qkv);
  // fused sliding-window attention: one wave per m
  swa_fused<<<8192, 256, 0, stream>>>(qkv, attn);
  // output projection: M=32768, N=512 -> 128 by x 2 bx = 256 blocks
  gemm256<0, 2><<<256, 512, 0, stream>>>(attn, Wob, bo, out);
}